// Round 8
// baseline (775.019 us; speedup 1.0000x reference)
//
#include <hip/hip_runtime.h>

#define IN_F 32
#define OUT_F 32
#define NREL 16
#define NBASES 8
#define WELEMS (NREL * IN_F * OUT_F)   // 16384 floats = 64 KB
#define WT_ROW 40                      // f16 elems per (r,o) row (80 B, 16B-aligned)
#define BIN_SHIFT 7
#define BIN_NODES 128                  // nodes per bin
#define CAP_BIN 4096                   // edges per bin capacity (mean 2048, 2x margin)

typedef _Float16 h2_t __attribute__((ext_vector_type(2)));

__device__ __forceinline__ float dot2h(unsigned int a, unsigned int b, float c) {
#if __has_builtin(__builtin_amdgcn_fdot2)
    return __builtin_amdgcn_fdot2(__builtin_bit_cast(h2_t, a),
                                  __builtin_bit_cast(h2_t, b), c, false);
#else
    h2_t av = __builtin_bit_cast(h2_t, a);
    h2_t bv = __builtin_bit_cast(h2_t, b);
    return fmaf((float)av.x, (float)bv.x, fmaf((float)av.y, (float)bv.y, c));
#endif
}

__device__ __forceinline__ unsigned short f2h(float x) {
    _Float16 h = (_Float16)x;
    return __builtin_bit_cast(unsigned short, h);
}

// ---------------------------------------------------------------------------
// Basis combination (validated R1-R7). W_eff[r][k][o] = w[r*1024 + k*32 + o].
// ---------------------------------------------------------------------------
__global__ void compute_w_kernel(const float* __restrict__ weight,
                                 const float* __restrict__ w_comp,
                                 float* __restrict__ w_out) {
    int idx = blockIdx.x * blockDim.x + threadIdx.x;
    if (idx >= WELEMS) return;
    int o = idx & 31;
    int r = (idx >> 5) & 15;
    int i = idx >> 9;
    float acc = 0.f;
#pragma unroll
    for (int b = 0; b < NBASES; ++b)
        acc += w_comp[r * NBASES + b] * weight[i * (NBASES * OUT_F) + b * OUT_F + o];
    w_out[idx] = acc;
}

__global__ void convert_x_kernel(const float* __restrict__ in,
                                 unsigned short* __restrict__ outh, int n4) {
    int i = blockIdx.x * blockDim.x + threadIdx.x;
    if (i >= n4) return;
    float4 v = reinterpret_cast<const float4*>(in)[i];
    ushort4 b;
    b.x = f2h(v.x); b.y = f2h(v.y); b.z = f2h(v.z); b.w = f2h(v.w);
    reinterpret_cast<ushort4*>(outh)[i] = b;
}

// ---------------------------------------------------------------------------
// Bin scatter: bin = dst>>7. Appends 8B records at per-bin cursors, so the
// active write set is ~NBINS cache lines (L2-resident) and lines fill fully
// -> ~8x less write traffic than the per-node-bucket scatter (R7: 100 MB).
// meta = src<<11 | rel<<7 | (dst&127); requires src < 2^17.
// ---------------------------------------------------------------------------
__global__ void scatter_bins_kernel(const int* __restrict__ src,
                                    const int* __restrict__ dst,
                                    const int* __restrict__ rel,
                                    const float* __restrict__ norm,
                                    int* __restrict__ cur,
                                    float2* __restrict__ brec, int E) {
    int i = blockIdx.x * blockDim.x + threadIdx.x;
    for (; i < E; i += gridDim.x * blockDim.x) {
        int d = dst[i];
        int b = d >> BIN_SHIFT;
        int pos = atomicAdd(&cur[b], 1);
        if (pos < CAP_BIN) {
            unsigned int meta = ((unsigned int)src[i] << 11) |
                                ((unsigned int)rel[i] << 7) |
                                (unsigned int)(d & (BIN_NODES - 1));
            brec[(size_t)b * CAP_BIN + pos] =
                make_float2(__uint_as_float(meta), norm[i]);
        }
    }
}

// ---------------------------------------------------------------------------
// Fused transform + reduce, one block per bin (128 dst nodes).
// LDS: W f16 [r][o][WT_ROW] (40 KB, R6-proven) + acc[128][32] f32 (16 KB).
// Per wave iteration: 2 edges (lane = hi*32 + o). Each lane computes the
// full k=32 dot via 16 v_dot2_f32_f16 and accumulates with one ds_add_f32
// (o spans banks 0..31 within each half-wave -> conflict-minimal; no serial
// register dependence, so iterations pipeline freely).
// Epilogue: one coalesced 16 KB store; every out row written exactly once.
// ---------------------------------------------------------------------------
__global__ __launch_bounds__(512) void rgcn_bin_kernel(
    const unsigned short* __restrict__ xh,   // [N][32] f16
    const float* __restrict__ w,             // f32 W_eff[r][k][o]
    const float2* __restrict__ brec,
    const int* __restrict__ cur,
    float* __restrict__ out, int N) {
    __shared__ __align__(16) unsigned short wtb[NREL * OUT_F * WT_ROW]; // 40 KB
    __shared__ float acc[BIN_NODES * OUT_F];                            // 16 KB
    const int b = blockIdx.x;

    for (int f = threadIdx.x; f < WELEMS; f += 512) {
        int o = f & 31;
        int k = (f >> 5) & 31;
        int r = f >> 10;
        wtb[(r * OUT_F + o) * WT_ROW + k] = f2h(w[f]);
    }
    for (int i = threadIdx.x; i < BIN_NODES * OUT_F; i += 512)
        acc[i] = 0.f;
    __syncthreads();

    const int lane = threadIdx.x & 63;
    const int o  = lane & 31;
    const int hi = lane >> 5;
    const int wid = threadIdx.x >> 6;              // 0..7
    const int c = min(cur[b], CAP_BIN);
    const float2* __restrict__ eb = brec + (size_t)b * CAP_BIN;
    const uint4* __restrict__ x4 = reinterpret_cast<const uint4*>(xh);

#pragma unroll 2
    for (int p = wid * 2; p < c; p += 16) {
        int e = p + hi;
        bool valid = (e < c);
        float2 rec = eb[valid ? e : (c - 1)];      // c>=1 inside loop
        unsigned int meta = __float_as_uint(rec.x);
        float nrm = valid ? rec.y : 0.f;
        int s  = meta >> 11;
        int r  = (meta >> 7) & 15;
        int dl = meta & (BIN_NODES - 1);
        const uint4* xp = x4 + (size_t)s * 4;
        uint4 X0 = xp[0], X1 = xp[1], X2 = xp[2], X3 = xp[3];
        const uint4* wr = reinterpret_cast<const uint4*>(
            &wtb[((r << 5) + o) * WT_ROW]);
        uint4 W0 = wr[0], W1 = wr[1], W2 = wr[2], W3 = wr[3];
        float q0, q1;
        q0 = dot2h(X0.x, W0.x, 0.f); q1 = dot2h(X2.x, W2.x, 0.f);
        q0 = dot2h(X0.y, W0.y, q0);  q1 = dot2h(X2.y, W2.y, q1);
        q0 = dot2h(X0.z, W0.z, q0);  q1 = dot2h(X2.z, W2.z, q1);
        q0 = dot2h(X0.w, W0.w, q0);  q1 = dot2h(X2.w, W2.w, q1);
        q0 = dot2h(X1.x, W1.x, q0);  q1 = dot2h(X3.x, W3.x, q1);
        q0 = dot2h(X1.y, W1.y, q0);  q1 = dot2h(X3.y, W3.y, q1);
        q0 = dot2h(X1.z, W1.z, q0);  q1 = dot2h(X3.z, W3.z, q1);
        q0 = dot2h(X1.w, W1.w, q0);  q1 = dot2h(X3.w, W3.w, q1);
        atomicAdd(&acc[dl * OUT_F + o], nrm * (q0 + q1));
    }
    __syncthreads();

    const size_t obase = (size_t)b * BIN_NODES * OUT_F;
    const size_t lim = (size_t)N * OUT_F;
    for (int i = threadIdx.x * 4; i < BIN_NODES * OUT_F; i += 512 * 4) {
        size_t g = obase + i;
        if (g < lim)
            *reinterpret_cast<float4*>(out + g) =
                *reinterpret_cast<const float4*>(&acc[i]);
    }
}

// ---------------------------------------------------------------------------
// Fallback (ws too small / N too big for meta packing): atomic path.
// ---------------------------------------------------------------------------
__global__ __launch_bounds__(512) void edge_scatter_kernel(
    const float* __restrict__ inputs, const float* __restrict__ w,
    const float* __restrict__ norm, const int* __restrict__ src,
    const int* __restrict__ dst, const int* __restrict__ rel,
    float* __restrict__ out, int nEdges) {
    __shared__ float wlds[WELEMS];
    {
        const float4* wsrc4 = reinterpret_cast<const float4*>(w);
        float4* wdst4 = reinterpret_cast<float4*>(wlds);
#pragma unroll
        for (int i = 0; i < 8; ++i)
            wdst4[threadIdx.x + i * 512] = wsrc4[threadIdx.x + i * 512];
    }
    __syncthreads();
    const int lane_o = (threadIdx.x & 7) * 4;
    const int eloc   = threadIdx.x >> 3;
    for (int ebase = blockIdx.x * 64; ebase < nEdges; ebase += gridDim.x * 64) {
        int e = ebase + eloc;
        if (e >= nEdges) continue;
        int s = src[e], d = dst[e], r = rel[e];
        float nrm = norm[e];
        const float* xrow = inputs + s * IN_F;
        const float* wrow = wlds + r * (IN_F * OUT_F) + lane_o;
        float ax = 0.f, ay = 0.f, az = 0.f, aw = 0.f;
#pragma unroll
        for (int k = 0; k < IN_F; ++k) {
            float x = xrow[k];
            float4 wv = *reinterpret_cast<const float4*>(wrow + k * OUT_F);
            ax += x * wv.x; ay += x * wv.y; az += x * wv.z; aw += x * wv.w;
        }
        float* op = out + d * OUT_F + lane_o;
        unsafeAtomicAdd(op + 0, ax * nrm);
        unsafeAtomicAdd(op + 1, ay * nrm);
        unsafeAtomicAdd(op + 2, az * nrm);
        unsafeAtomicAdd(op + 3, aw * nrm);
    }
}

extern "C" void kernel_launch(void* const* d_in, const int* in_sizes, int n_in,
                              void* d_out, int out_size, void* d_ws, size_t ws_size,
                              hipStream_t stream) {
    const float* inputs = (const float*)d_in[0];   // [N, 32]
    const float* weight = (const float*)d_in[1];   // [8, 32, 32]
    const float* w_comp = (const float*)d_in[2];   // [16, 8]
    const float* norm   = (const float*)d_in[3];   // [E, 1]
    const int*   src    = (const int*)d_in[4];     // [E]
    const int*   dst    = (const int*)d_in[5];     // [E]
    const int*   rel    = (const int*)d_in[6];     // [E]
    float* out = (float*)d_out;                    // [N, 32]

    const int E = in_sizes[4];
    const int N = in_sizes[0] / IN_F;
    const int NBINS = (N + BIN_NODES - 1) >> BIN_SHIFT;

    // ws layout (bytes):
    //   [0, 64K)        w (f32 combined weights)
    //   xh              N*32 f16
    //   brec            NBINS*CAP_BIN float2
    //   cur             NBINS int
    char* base = (char*)d_ws;
    float* w_ws = (float*)base;
    size_t o_xh   = 65536;
    size_t o_brec = (o_xh + (size_t)N * IN_F * 2 + 255) & ~(size_t)255;
    size_t o_cur  = (o_brec + (size_t)NBINS * CAP_BIN * 8 + 255) & ~(size_t)255;
    size_t need   = o_cur + (size_t)NBINS * 4;

    compute_w_kernel<<<WELEMS / 256, 256, 0, stream>>>(weight, w_comp, w_ws);

    if (ws_size >= need && N <= (1 << 17)) {
        unsigned short* xh   = (unsigned short*)(base + o_xh);
        float2*         brec = (float2*)(base + o_brec);
        int*            cur  = (int*)(base + o_cur);

        const int n4 = (N * IN_F) / 4;
        convert_x_kernel<<<(n4 + 255) / 256, 256, 0, stream>>>(inputs, xh, n4);
        hipMemsetAsync(cur, 0, (size_t)NBINS * sizeof(int), stream);
        scatter_bins_kernel<<<2048, 256, 0, stream>>>(src, dst, rel, norm,
                                                      cur, brec, E);
        rgcn_bin_kernel<<<NBINS, 512, 0, stream>>>(xh, w_ws, brec, cur, out, N);
    } else {
        hipMemsetAsync(d_out, 0, (size_t)out_size * sizeof(float), stream);
        edge_scatter_kernel<<<4096, 512, 0, stream>>>(inputs, w_ws, norm, src,
                                                      dst, rel, out, E);
    }
}

// Round 9
// 518.589 us; speedup vs baseline: 1.4945x; 1.4945x over previous
//
#include <hip/hip_runtime.h>

#define IN_F 32
#define OUT_F 32
#define NREL 16
#define NBASES 8
#define WELEMS (NREL * IN_F * OUT_F)   // 16384 floats = 64 KB
#define WT_ROW 40                      // f16 elems per (r,o) row (80 B, 16B-aligned)
#define BIN_SHIFT 7
#define BIN_NODES 128                  // nodes per bin
#define CAP_BIN 4096                   // edges/bin capacity (mean 2048, max ~2300)

typedef _Float16 h2_t __attribute__((ext_vector_type(2)));

__device__ __forceinline__ float dot2h(unsigned int a, unsigned int b, float c) {
#if __has_builtin(__builtin_amdgcn_fdot2)
    return __builtin_amdgcn_fdot2(__builtin_bit_cast(h2_t, a),
                                  __builtin_bit_cast(h2_t, b), c, false);
#else
    h2_t av = __builtin_bit_cast(h2_t, a);
    h2_t bv = __builtin_bit_cast(h2_t, b);
    return fmaf((float)av.x, (float)bv.x, fmaf((float)av.y, (float)bv.y, c));
#endif
}

__device__ __forceinline__ unsigned short f2h(float x) {
    _Float16 h = (_Float16)x;
    return __builtin_bit_cast(unsigned short, h);
}

// ---------------------------------------------------------------------------
// Basis combination (validated R1-R8). W_eff[r][k][o] = w[r*1024 + k*32 + o].
// ---------------------------------------------------------------------------
__global__ void compute_w_kernel(const float* __restrict__ weight,
                                 const float* __restrict__ w_comp,
                                 float* __restrict__ w_out) {
    int idx = blockIdx.x * blockDim.x + threadIdx.x;
    if (idx >= WELEMS) return;
    int o = idx & 31;
    int r = (idx >> 5) & 15;
    int i = idx >> 9;
    float acc = 0.f;
#pragma unroll
    for (int b = 0; b < NBASES; ++b)
        acc += w_comp[r * NBASES + b] * weight[i * (NBASES * OUT_F) + b * OUT_F + o];
    w_out[idx] = acc;
}

__global__ void convert_x_kernel(const float* __restrict__ in,
                                 unsigned short* __restrict__ outh, int n4) {
    int i = blockIdx.x * blockDim.x + threadIdx.x;
    if (i >= n4) return;
    float4 v = reinterpret_cast<const float4*>(in)[i];
    ushort4 b;
    b.x = f2h(v.x); b.y = f2h(v.y); b.z = f2h(v.z); b.w = f2h(v.w);
    reinterpret_cast<ushort4*>(outh)[i] = b;
}

// ---------------------------------------------------------------------------
// Bin scatter (R8-proven fast): bin = dst>>7; active write set ~NBINS hot
// lines (L2-resident). meta = src<<11 | rel<<7 | (dst&127); src < 2^17.
// Note meta>>7 == src*16+rel == hidx into h_rel.
// ---------------------------------------------------------------------------
__global__ void scatter_bins_kernel(const int* __restrict__ src,
                                    const int* __restrict__ dst,
                                    const int* __restrict__ rel,
                                    const float* __restrict__ norm,
                                    int* __restrict__ cur,
                                    float2* __restrict__ brec, int E) {
    int i = blockIdx.x * blockDim.x + threadIdx.x;
    for (; i < E; i += gridDim.x * blockDim.x) {
        int d = dst[i];
        int b = d >> BIN_SHIFT;
        int pos = atomicAdd(&cur[b], 1);
        if (pos < CAP_BIN) {
            unsigned int meta = ((unsigned int)src[i] << 11) |
                                ((unsigned int)rel[i] << 7) |
                                (unsigned int)(d & (BIN_NODES - 1));
            brec[(size_t)b * CAP_BIN + pos] =
                make_float2(__uint_as_float(meta), norm[i]);
        }
    }
}

// ---------------------------------------------------------------------------
// Per-bin LDS counting sort by local dst -> dense CSR segments, in place.
// Writes rs[d] (global record base) and cnt[d] (degree) for the 128 nodes.
// ---------------------------------------------------------------------------
__global__ __launch_bounds__(256) void bin_sort_kernel(
    const int* __restrict__ cur, float2* __restrict__ brec,
    int* __restrict__ rs, int* __restrict__ cnt, int N) {
    __shared__ float2 recs[CAP_BIN];        // 32 KB stage
    __shared__ int cnts[BIN_NODES];
    __shared__ int pref[BIN_NODES];
    const int b = blockIdx.x;
    const int c = min(cur[b], CAP_BIN);
    float2* gb = brec + (size_t)b * CAP_BIN;

    for (int i = threadIdx.x; i < c; i += 256) recs[i] = gb[i];
    if (threadIdx.x < BIN_NODES) cnts[threadIdx.x] = 0;
    __syncthreads();
    for (int i = threadIdx.x; i < c; i += 256)
        atomicAdd(&cnts[__float_as_uint(recs[i].x) & (BIN_NODES - 1)], 1);
    __syncthreads();
    if (threadIdx.x < BIN_NODES) pref[threadIdx.x] = cnts[threadIdx.x];
    __syncthreads();
    for (int off = 1; off < BIN_NODES; off <<= 1) {     // inclusive scan
        int v = 0;
        if (threadIdx.x < BIN_NODES) {
            v = pref[threadIdx.x];
            if (threadIdx.x >= off) v += pref[threadIdx.x - off];
        }
        __syncthreads();
        if (threadIdx.x < BIN_NODES) pref[threadIdx.x] = v;
        __syncthreads();
    }
    if (threadIdx.x < BIN_NODES) {
        int excl = pref[threadIdx.x] - cnts[threadIdx.x];
        int d = b * BIN_NODES + threadIdx.x;
        if (d < N) {
            rs[d]  = b * CAP_BIN + excl;
            cnt[d] = cnts[threadIdx.x];
        }
        cnts[threadIdx.x] = excl;           // becomes scatter cursor
    }
    __syncthreads();
    for (int i = threadIdx.x; i < c; i += 256) {
        float2 r = recs[i];
        int dl = __float_as_uint(r.x) & (BIN_NODES - 1);
        int pos = atomicAdd(&cnts[dl], 1);
        gb[pos] = r;                         // in place: source staged in LDS
    }
}

// ---------------------------------------------------------------------------
// Dense h_rel GEMM (R7-proven). h_rel[n][r][o] = sum_k x[n][k]*W_eff[r][k][o].
// One wave per 4 nodes; W f16 in LDS [r][o][WT_ROW] (40 KB); each W b128
// read amortized across 4 nodes.
// ---------------------------------------------------------------------------
__global__ __launch_bounds__(512) void hrel_gemm_kernel(
    const unsigned short* __restrict__ xh,   // [N][32] f16
    const float* __restrict__ w,             // f32 W_eff[r][k][o]
    unsigned short* __restrict__ hrel,       // [N*16][32] f16
    int N) {
    __shared__ __align__(16) unsigned short wt[NREL * OUT_F * WT_ROW]; // 40 KB
    for (int f = threadIdx.x; f < WELEMS; f += 512) {
        int o = f & 31;
        int k = (f >> 5) & 31;
        int r = f >> 10;
        wt[(r * OUT_F + o) * WT_ROW + k] = f2h(w[f]);
    }
    __syncthreads();

    const int lane = threadIdx.x & 63;
    const int o  = lane & 31;
    const int hi = lane >> 5;                 // relation half: r = hi*8 + j
    int wv = (blockIdx.x * 512 + threadIdx.x) >> 6;
    const int nw = (gridDim.x * 512) >> 6;
    const uint4* __restrict__ x4 = reinterpret_cast<const uint4*>(xh);

    for (int nb = wv * 4; nb < N; nb += nw * 4) {
        uint4 X[4][4];
#pragma unroll
        for (int i = 0; i < 4; ++i) {
            int n = min(nb + i, N - 1);
            const uint4* xp = x4 + (size_t)n * 4;
            X[i][0] = xp[0]; X[i][1] = xp[1]; X[i][2] = xp[2]; X[i][3] = xp[3];
        }
#pragma unroll 2
        for (int j = 0; j < 8; ++j) {
            const int r = hi * 8 + j;
            const uint4* wr = reinterpret_cast<const uint4*>(
                &wt[((r << 5) + o) * WT_ROW]);
            uint4 W0 = wr[0], W1 = wr[1], W2 = wr[2], W3 = wr[3];
#pragma unroll
            for (int i = 0; i < 4; ++i) {
                float q;
                q = dot2h(X[i][0].x, W0.x, 0.f);
                q = dot2h(X[i][0].y, W0.y, q);
                q = dot2h(X[i][0].z, W0.z, q);
                q = dot2h(X[i][0].w, W0.w, q);
                q = dot2h(X[i][1].x, W1.x, q);
                q = dot2h(X[i][1].y, W1.y, q);
                q = dot2h(X[i][1].z, W1.z, q);
                q = dot2h(X[i][1].w, W1.w, q);
                q = dot2h(X[i][2].x, W2.x, q);
                q = dot2h(X[i][2].y, W2.y, q);
                q = dot2h(X[i][2].z, W2.z, q);
                q = dot2h(X[i][2].w, W2.w, q);
                q = dot2h(X[i][3].x, W3.x, q);
                q = dot2h(X[i][3].y, W3.y, q);
                q = dot2h(X[i][3].z, W3.z, q);
                q = dot2h(X[i][3].w, W3.w, q);
                if (nb + i < N)
                    hrel[((size_t)(nb + i) * NREL + r) * OUT_F + o] = f2h(q);
            }
        }
    }
}

// ---------------------------------------------------------------------------
// Half-wave gather: 32 lanes per node (lane = output col o). Records are
// dense CSR segments (bin_sort). Load up to 32 records with ONE coalesced
// read; per record: shfl-broadcast meta/norm + one coalesced 64B h_rel line
// (lane o reads element o) + one fma. 3.2M threads -> deep latency hiding.
// ---------------------------------------------------------------------------
__global__ __launch_bounds__(512) void gather_half_kernel(
    const unsigned short* __restrict__ hrel,
    const float2* __restrict__ edata,
    const int* __restrict__ rs, const int* __restrict__ cnt,
    float* __restrict__ out, int N) {
    const int half_id = (blockIdx.x * 512 + threadIdx.x) >> 5;
    const int o = threadIdx.x & 31;
    if (half_id >= N) return;
    const int d = half_id;
    const int beg = rs[d];
    const int c = cnt[d];
    float acc = 0.f;
    if (c > 0) {
        const int cc = min(c, 32);
        float2 rec = edata[beg + min(o, cc - 1)];
        unsigned int mymeta = __float_as_uint(rec.x);
        float mynrm = rec.y;
        for (int i = 0; i < cc; ++i) {
            unsigned int meta = __shfl(mymeta, i, 32);
            float nrm = __shfl(mynrm, i, 32);
            float h = (float)__builtin_bit_cast(
                _Float16, hrel[(size_t)(meta >> 7) * OUT_F + o]);
            acc = fmaf(nrm, h, acc);
        }
        for (int i = 32; i < c; ++i) {       // rare (deg > 32)
            float2 r2 = edata[beg + i];
            unsigned int meta = __float_as_uint(r2.x);
            float h = (float)__builtin_bit_cast(
                _Float16, hrel[(size_t)(meta >> 7) * OUT_F + o]);
            acc = fmaf(r2.y, h, acc);
        }
    }
    out[(size_t)d * OUT_F + o] = acc;
}

// ---------------------------------------------------------------------------
// Fallback (ws too small / N too big for meta packing): atomic path.
// ---------------------------------------------------------------------------
__global__ __launch_bounds__(512) void edge_scatter_kernel(
    const float* __restrict__ inputs, const float* __restrict__ w,
    const float* __restrict__ norm, const int* __restrict__ src,
    const int* __restrict__ dst, const int* __restrict__ rel,
    float* __restrict__ out, int nEdges) {
    __shared__ float wlds[WELEMS];
    {
        const float4* wsrc4 = reinterpret_cast<const float4*>(w);
        float4* wdst4 = reinterpret_cast<float4*>(wlds);
#pragma unroll
        for (int i = 0; i < 8; ++i)
            wdst4[threadIdx.x + i * 512] = wsrc4[threadIdx.x + i * 512];
    }
    __syncthreads();
    const int lane_o = (threadIdx.x & 7) * 4;
    const int eloc   = threadIdx.x >> 3;
    for (int ebase = blockIdx.x * 64; ebase < nEdges; ebase += gridDim.x * 64) {
        int e = ebase + eloc;
        if (e >= nEdges) continue;
        int s = src[e], d = dst[e], r = rel[e];
        float nrm = norm[e];
        const float* xrow = inputs + s * IN_F;
        const float* wrow = wlds + r * (IN_F * OUT_F) + lane_o;
        float ax = 0.f, ay = 0.f, az = 0.f, aw = 0.f;
#pragma unroll
        for (int k = 0; k < IN_F; ++k) {
            float x = xrow[k];
            float4 wv = *reinterpret_cast<const float4*>(wrow + k * OUT_F);
            ax += x * wv.x; ay += x * wv.y; az += x * wv.z; aw += x * wv.w;
        }
        float* op = out + d * OUT_F + lane_o;
        unsafeAtomicAdd(op + 0, ax * nrm);
        unsafeAtomicAdd(op + 1, ay * nrm);
        unsafeAtomicAdd(op + 2, az * nrm);
        unsafeAtomicAdd(op + 3, aw * nrm);
    }
}

extern "C" void kernel_launch(void* const* d_in, const int* in_sizes, int n_in,
                              void* d_out, int out_size, void* d_ws, size_t ws_size,
                              hipStream_t stream) {
    const float* inputs = (const float*)d_in[0];   // [N, 32]
    const float* weight = (const float*)d_in[1];   // [8, 32, 32]
    const float* w_comp = (const float*)d_in[2];   // [16, 8]
    const float* norm   = (const float*)d_in[3];   // [E, 1]
    const int*   src    = (const int*)d_in[4];     // [E]
    const int*   dst    = (const int*)d_in[5];     // [E]
    const int*   rel    = (const int*)d_in[6];     // [E]
    float* out = (float*)d_out;                    // [N, 32]

    const int E = in_sizes[4];
    const int N = in_sizes[0] / IN_F;
    const int NBINS = (N + BIN_NODES - 1) >> BIN_SHIFT;

    // ws layout (bytes):
    //   [0, 64K)   w (f32 combined weights)
    //   xh         N*32 f16
    //   hrel       N*16*32 f16
    //   brec       NBINS*CAP_BIN float2
    //   cur        NBINS int; rs N int; cnt N int
    char* base = (char*)d_ws;
    float* w_ws = (float*)base;
    size_t o_xh   = 65536;
    size_t o_hrel = (o_xh + (size_t)N * IN_F * 2 + 255) & ~(size_t)255;
    size_t o_brec = (o_hrel + (size_t)N * NREL * OUT_F * 2 + 255) & ~(size_t)255;
    size_t o_cur  = (o_brec + (size_t)NBINS * CAP_BIN * 8 + 255) & ~(size_t)255;
    size_t o_rs   = o_cur + (size_t)NBINS * 4;
    size_t o_cnt  = o_rs + (size_t)N * 4;
    size_t need   = o_cnt + (size_t)N * 4;

    compute_w_kernel<<<WELEMS / 256, 256, 0, stream>>>(weight, w_comp, w_ws);

    if (ws_size >= need && N <= (1 << 17)) {
        unsigned short* xh   = (unsigned short*)(base + o_xh);
        unsigned short* hrel = (unsigned short*)(base + o_hrel);
        float2*         brec = (float2*)(base + o_brec);
        int*            cur  = (int*)(base + o_cur);
        int*            rs   = (int*)(base + o_rs);
        int*            cnt  = (int*)(base + o_cnt);

        const int n4 = (N * IN_F) / 4;
        convert_x_kernel<<<(n4 + 255) / 256, 256, 0, stream>>>(inputs, xh, n4);
        hipMemsetAsync(cur, 0, (size_t)NBINS * sizeof(int), stream);
        scatter_bins_kernel<<<2048, 256, 0, stream>>>(src, dst, rel, norm,
                                                      cur, brec, E);
        bin_sort_kernel<<<NBINS, 256, 0, stream>>>(cur, brec, rs, cnt, N);
        hrel_gemm_kernel<<<1024, 512, 0, stream>>>(xh, w_ws, hrel, N);
        gather_half_kernel<<<(N * 32 + 511) / 512, 512, 0, stream>>>(
            hrel, brec, rs, cnt, out, N);
    } else {
        hipMemsetAsync(d_out, 0, (size_t)out_size * sizeof(float), stream);
        edge_scatter_kernel<<<4096, 512, 0, stream>>>(inputs, w_ws, norm, src,
                                                      dst, rel, out, E);
    }
}

// Round 10
// 434.444 us; speedup vs baseline: 1.7839x; 1.1937x over previous
//
#include <hip/hip_runtime.h>

#define IN_F 32
#define OUT_F 32
#define NREL 16
#define NBASES 8
#define WELEMS (NREL * IN_F * OUT_F)   // 16384 floats = 64 KB
#define WT_ROW 40                      // f16 elems per (r,o) row (80 B)
#define TILE_E 4096                    // edges per sort tile
#define BIN_SHIFT 7
#define BIN_NODES 128
#define PBINS 1024                     // padded bin count (pow2 >= N/128)

typedef _Float16 h2_t __attribute__((ext_vector_type(2)));

__device__ __forceinline__ float dot2h(unsigned int a, unsigned int b, float c) {
#if __has_builtin(__builtin_amdgcn_fdot2)
    return __builtin_amdgcn_fdot2(__builtin_bit_cast(h2_t, a),
                                  __builtin_bit_cast(h2_t, b), c, false);
#else
    h2_t av = __builtin_bit_cast(h2_t, a);
    h2_t bv = __builtin_bit_cast(h2_t, b);
    return fmaf((float)av.x, (float)bv.x, fmaf((float)av.y, (float)bv.y, c));
#endif
}

__device__ __forceinline__ unsigned short f2h(float x) {
    _Float16 h = (_Float16)x;
    return __builtin_bit_cast(unsigned short, h);
}

// ---------------------------------------------------------------------------
// Basis combination (validated R1-R9). W_eff[r][k][o] = w[r*1024 + k*32 + o].
// ---------------------------------------------------------------------------
__global__ void compute_w_kernel(const float* __restrict__ weight,
                                 const float* __restrict__ w_comp,
                                 float* __restrict__ w_out) {
    int idx = blockIdx.x * blockDim.x + threadIdx.x;
    if (idx >= WELEMS) return;
    int o = idx & 31;
    int r = (idx >> 5) & 15;
    int i = idx >> 9;
    float acc = 0.f;
#pragma unroll
    for (int b = 0; b < NBASES; ++b)
        acc += w_comp[r * NBASES + b] * weight[i * (NBASES * OUT_F) + b * OUT_F + o];
    w_out[idx] = acc;
}

__global__ void convert_x_kernel(const float* __restrict__ in,
                                 unsigned short* __restrict__ outh, int n4) {
    int i = blockIdx.x * blockDim.x + threadIdx.x;
    if (i >= n4) return;
    float4 v = reinterpret_cast<const float4*>(in)[i];
    ushort4 b;
    b.x = f2h(v.x); b.y = f2h(v.y); b.z = f2h(v.z); b.w = f2h(v.w);
    reinterpret_cast<ushort4*>(outh)[i] = b;
}

// ---------------------------------------------------------------------------
// Tile-local bin sort: block t owns edges [t*4096, ...). LDS hist over 1024
// bins -> LDS scan -> LDS reorder -> sequential coalesced writeback. No
// global atomics; LDS cursor chains are ~4 deep. Directory (bin-major):
// dir[b*T + t] = { local_base_within_tile, count }.
// meta = src<<11 | rel<<7 | (dst&127);  meta>>7 == src*16+rel (h_rel row).
// ---------------------------------------------------------------------------
__global__ __launch_bounds__(256) void tile_sort_kernel(
    const int* __restrict__ src, const int* __restrict__ dst,
    const int* __restrict__ rel, const float* __restrict__ norm,
    float2* __restrict__ grecs, uint2* __restrict__ dir, int E, int T) {
    __shared__ float2 recs[TILE_E];      // 32 KB
    __shared__ int hist[PBINS];          // 4 KB
    __shared__ int bbase[PBINS];         // 4 KB
    __shared__ int partial[256];
    const int t = blockIdx.x;
    const int e0 = t * TILE_E;
    const int ct = min(TILE_E, E - e0);

    for (int i = threadIdx.x; i < PBINS; i += 256) hist[i] = 0;
    __syncthreads();
    for (int i = threadIdx.x; i < ct; i += 256)
        atomicAdd(&hist[dst[e0 + i] >> BIN_SHIFT], 1);
    __syncthreads();

    // exclusive scan of hist[1024] with 256 threads (4 bins/thread)
    int loc[4], tsum = 0;
    {
        int i0 = threadIdx.x * 4;
#pragma unroll
        for (int k = 0; k < 4; ++k) { loc[k] = tsum; tsum += hist[i0 + k]; }
        partial[threadIdx.x] = tsum;
    }
    __syncthreads();
    for (int off = 1; off < 256; off <<= 1) {
        int v = partial[threadIdx.x];
        int add = (threadIdx.x >= off) ? partial[threadIdx.x - off] : 0;
        __syncthreads();
        partial[threadIdx.x] = v + add;
        __syncthreads();
    }
    {
        int excl = partial[threadIdx.x] - tsum;
        int i0 = threadIdx.x * 4;
#pragma unroll
        for (int k = 0; k < 4; ++k) bbase[i0 + k] = excl + loc[k];
    }
    __syncthreads();

    // directory write (bin-major) + convert hist into cursor (=base)
    for (int b = threadIdx.x; b < PBINS; b += 256) {
        dir[(size_t)b * T + t] = make_uint2((unsigned)bbase[b], (unsigned)hist[b]);
        hist[b] = bbase[b];
    }
    __syncthreads();

    // LDS reorder
    for (int i = threadIdx.x; i < ct; i += 256) {
        int e = e0 + i;
        int d = dst[e];
        int pos = atomicAdd(&hist[d >> BIN_SHIFT], 1);
        unsigned meta = ((unsigned)src[e] << 11) | ((unsigned)rel[e] << 7) |
                        (unsigned)(d & (BIN_NODES - 1));
        recs[pos] = make_float2(__uint_as_float(meta), norm[e]);
    }
    __syncthreads();

    float2* g = grecs + (size_t)t * TILE_E;
    for (int i = threadIdx.x; i < ct; i += 256) g[i] = recs[i];
}

// ---------------------------------------------------------------------------
// Dense h_rel GEMM (R7-proven). h_rel[n][r][o] = sum_k x[n][k]*W_eff[r][k][o].
// ---------------------------------------------------------------------------
__global__ __launch_bounds__(512) void hrel_gemm_kernel(
    const unsigned short* __restrict__ xh,   // [N][32] f16
    const float* __restrict__ w,             // f32 W_eff[r][k][o]
    unsigned short* __restrict__ hrel,       // [N*16][32] f16
    int N) {
    __shared__ __align__(16) unsigned short wt[NREL * OUT_F * WT_ROW]; // 40 KB
    for (int f = threadIdx.x; f < WELEMS; f += 512) {
        int o = f & 31;
        int k = (f >> 5) & 31;
        int r = f >> 10;
        wt[(r * OUT_F + o) * WT_ROW + k] = f2h(w[f]);
    }
    __syncthreads();

    const int lane = threadIdx.x & 63;
    const int o  = lane & 31;
    const int hi = lane >> 5;
    int wv = (blockIdx.x * 512 + threadIdx.x) >> 6;
    const int nw = (gridDim.x * 512) >> 6;
    const uint4* __restrict__ x4 = reinterpret_cast<const uint4*>(xh);

    for (int nb = wv * 4; nb < N; nb += nw * 4) {
        uint4 X[4][4];
#pragma unroll
        for (int i = 0; i < 4; ++i) {
            int n = min(nb + i, N - 1);
            const uint4* xp = x4 + (size_t)n * 4;
            X[i][0] = xp[0]; X[i][1] = xp[1]; X[i][2] = xp[2]; X[i][3] = xp[3];
        }
#pragma unroll 2
        for (int j = 0; j < 8; ++j) {
            const int r = hi * 8 + j;
            const uint4* wr = reinterpret_cast<const uint4*>(
                &wt[((r << 5) + o) * WT_ROW]);
            uint4 W0 = wr[0], W1 = wr[1], W2 = wr[2], W3 = wr[3];
#pragma unroll
            for (int i = 0; i < 4; ++i) {
                float q;
                q = dot2h(X[i][0].x, W0.x, 0.f);
                q = dot2h(X[i][0].y, W0.y, q);
                q = dot2h(X[i][0].z, W0.z, q);
                q = dot2h(X[i][0].w, W0.w, q);
                q = dot2h(X[i][1].x, W1.x, q);
                q = dot2h(X[i][1].y, W1.y, q);
                q = dot2h(X[i][1].z, W1.z, q);
                q = dot2h(X[i][1].w, W1.w, q);
                q = dot2h(X[i][2].x, W2.x, q);
                q = dot2h(X[i][2].y, W2.y, q);
                q = dot2h(X[i][2].z, W2.z, q);
                q = dot2h(X[i][2].w, W2.w, q);
                q = dot2h(X[i][3].x, W3.x, q);
                q = dot2h(X[i][3].y, W3.y, q);
                q = dot2h(X[i][3].z, W3.z, q);
                q = dot2h(X[i][3].w, W3.w, q);
                if (nb + i < N)
                    hrel[((size_t)(nb + i) * NREL + r) * OUT_F + o] = f2h(q);
            }
        }
    }
}

// ---------------------------------------------------------------------------
// Gather: block per bin (128 dst nodes), out accumulators in LDS (16 KB).
// 16 half-waves (lane = output col o) walk the bin's T directory slices;
// per record: broadcast 8B read + one coalesced 64B h_rel line (L3-resident)
// + one fire-and-forget ds f32 add (banks 0..31 distinct per half-wave).
// Epilogue: one coalesced 16 KB store; every out row written exactly once.
// ---------------------------------------------------------------------------
__global__ __launch_bounds__(512) void gather_bins_kernel(
    const unsigned short* __restrict__ hrel,
    const float2* __restrict__ grecs,
    const uint2* __restrict__ dir,
    float* __restrict__ out, int N, int T) {
    __shared__ float accs[BIN_NODES * OUT_F];   // 16 KB
    const int b = blockIdx.x;
    for (int i = threadIdx.x; i < BIN_NODES * OUT_F; i += 512) accs[i] = 0.f;
    __syncthreads();

    const int hw = threadIdx.x >> 5;
    const int o  = threadIdx.x & 31;
    const uint2* __restrict__ drow = dir + (size_t)b * T;

    for (int t = hw; t < T; t += 16) {
        uint2 dr = drow[t];
        int cnt = (int)dr.y;
        if (cnt == 0) continue;
        const float2* __restrict__ rp = grecs + (size_t)t * TILE_E + dr.x;
#pragma unroll 2
        for (int j = 0; j < cnt; ++j) {
            float2 rec = rp[j];
            unsigned meta = __float_as_uint(rec.x);
            float h = (float)__builtin_bit_cast(
                _Float16, hrel[(size_t)(meta >> 7) * OUT_F + o]);
            atomicAdd(&accs[(meta & (BIN_NODES - 1)) * OUT_F + o], rec.y * h);
        }
    }
    __syncthreads();

    const size_t lim = (size_t)N * OUT_F;
    const size_t obase = (size_t)b * BIN_NODES * OUT_F;
    for (int i = threadIdx.x * 4; i < BIN_NODES * OUT_F; i += 512 * 4) {
        size_t g = obase + i;
        if (g < lim)
            *reinterpret_cast<float4*>(out + g) =
                *reinterpret_cast<const float4*>(&accs[i]);
    }
}

// ---------------------------------------------------------------------------
// Fallback (ws too small / N too big): atomic path (proven).
// ---------------------------------------------------------------------------
__global__ __launch_bounds__(512) void edge_scatter_kernel(
    const float* __restrict__ inputs, const float* __restrict__ w,
    const float* __restrict__ norm, const int* __restrict__ src,
    const int* __restrict__ dst, const int* __restrict__ rel,
    float* __restrict__ out, int nEdges) {
    __shared__ float wlds[WELEMS];
    {
        const float4* wsrc4 = reinterpret_cast<const float4*>(w);
        float4* wdst4 = reinterpret_cast<float4*>(wlds);
#pragma unroll
        for (int i = 0; i < 8; ++i)
            wdst4[threadIdx.x + i * 512] = wsrc4[threadIdx.x + i * 512];
    }
    __syncthreads();
    const int lane_o = (threadIdx.x & 7) * 4;
    const int eloc   = threadIdx.x >> 3;
    for (int ebase = blockIdx.x * 64; ebase < nEdges; ebase += gridDim.x * 64) {
        int e = ebase + eloc;
        if (e >= nEdges) continue;
        int s = src[e], d = dst[e], r = rel[e];
        float nrm = norm[e];
        const float* xrow = inputs + s * IN_F;
        const float* wrow = wlds + r * (IN_F * OUT_F) + lane_o;
        float ax = 0.f, ay = 0.f, az = 0.f, aw = 0.f;
#pragma unroll
        for (int k = 0; k < IN_F; ++k) {
            float x = xrow[k];
            float4 wv = *reinterpret_cast<const float4*>(wrow + k * OUT_F);
            ax += x * wv.x; ay += x * wv.y; az += x * wv.z; aw += x * wv.w;
        }
        float* op = out + d * OUT_F + lane_o;
        unsafeAtomicAdd(op + 0, ax * nrm);
        unsafeAtomicAdd(op + 1, ay * nrm);
        unsafeAtomicAdd(op + 2, az * nrm);
        unsafeAtomicAdd(op + 3, aw * nrm);
    }
}

extern "C" void kernel_launch(void* const* d_in, const int* in_sizes, int n_in,
                              void* d_out, int out_size, void* d_ws, size_t ws_size,
                              hipStream_t stream) {
    const float* inputs = (const float*)d_in[0];   // [N, 32]
    const float* weight = (const float*)d_in[1];   // [8, 32, 32]
    const float* w_comp = (const float*)d_in[2];   // [16, 8]
    const float* norm   = (const float*)d_in[3];   // [E, 1]
    const int*   src    = (const int*)d_in[4];     // [E]
    const int*   dst    = (const int*)d_in[5];     // [E]
    const int*   rel    = (const int*)d_in[6];     // [E]
    float* out = (float*)d_out;                    // [N, 32]

    const int E = in_sizes[4];
    const int N = in_sizes[0] / IN_F;
    const int T = (E + TILE_E - 1) / TILE_E;
    const int NBINS = (N + BIN_NODES - 1) >> BIN_SHIFT;

    // ws layout (bytes):
    //   [0, 64K)   w (f32 combined weights)
    //   xh         N*32 f16
    //   hrel       N*16*32 f16
    //   grecs      T*TILE_E float2
    //   dir        PBINS*T uint2
    char* base = (char*)d_ws;
    float* w_ws = (float*)base;
    size_t o_xh    = 65536;
    size_t o_hrel  = (o_xh + (size_t)N * IN_F * 2 + 255) & ~(size_t)255;
    size_t o_grecs = (o_hrel + (size_t)N * NREL * OUT_F * 2 + 255) & ~(size_t)255;
    size_t o_dir   = (o_grecs + (size_t)T * TILE_E * 8 + 255) & ~(size_t)255;
    size_t need    = o_dir + (size_t)PBINS * T * 8;

    compute_w_kernel<<<WELEMS / 256, 256, 0, stream>>>(weight, w_comp, w_ws);

    if (ws_size >= need && N <= PBINS * BIN_NODES) {
        unsigned short* xh    = (unsigned short*)(base + o_xh);
        unsigned short* hrel  = (unsigned short*)(base + o_hrel);
        float2*         grecs = (float2*)(base + o_grecs);
        uint2*          dirp  = (uint2*)(base + o_dir);

        const int n4 = (N * IN_F) / 4;
        convert_x_kernel<<<(n4 + 255) / 256, 256, 0, stream>>>(inputs, xh, n4);
        tile_sort_kernel<<<T, 256, 0, stream>>>(src, dst, rel, norm,
                                                grecs, dirp, E, T);
        hrel_gemm_kernel<<<1024, 512, 0, stream>>>(xh, w_ws, hrel, N);
        gather_bins_kernel<<<NBINS, 512, 0, stream>>>(hrel, grecs, dirp,
                                                      out, N, T);
    } else {
        hipMemsetAsync(d_out, 0, (size_t)out_size * sizeof(float), stream);
        edge_scatter_kernel<<<4096, 512, 0, stream>>>(inputs, w_ws, norm, src,
                                                      dst, rel, out, E);
    }
}